// Round 6
// baseline (312.551 us; speedup 1.0000x reference)
//
#include <hip/hip_runtime.h>
#include <stdint.h>

#define NN 50000
#define NE 800000
#define CH 512

__device__ __forceinline__ unsigned short f2bf(float f) {
    union { float f; unsigned u; } v; v.f = f;
    unsigned u = v.u;
    unsigned r = u + 0x7FFFu + ((u >> 16) & 1u);
    return (unsigned short)(r >> 16);
}

__device__ __forceinline__ float u2f(unsigned u) {
    union { unsigned u; float f; } v; v.u = u;
    return v.f;
}

typedef short bf16x8 __attribute__((ext_vector_type(8)));
typedef float f32x4 __attribute__((ext_vector_type(4)));
typedef float f32x4e __attribute__((ext_vector_type(4)));
typedef unsigned u32x4e __attribute__((ext_vector_type(4)));

// ---------------- xb = bf16(x) ----------------
__global__ void conv_x(const f32x4e* __restrict__ x, u32x4e* __restrict__ xb, int n8) {
    int i = blockIdx.x * 256 + threadIdx.x;
    if (i >= n8) return;
    f32x4e a = __builtin_nontemporal_load(&x[2 * i]);
    f32x4e b = __builtin_nontemporal_load(&x[2 * i + 1]);
    u32x4e o;
    o.x = (unsigned)f2bf(a.x) | ((unsigned)f2bf(a.y) << 16);
    o.y = (unsigned)f2bf(a.z) | ((unsigned)f2bf(a.w) << 16);
    o.z = (unsigned)f2bf(b.x) | ((unsigned)f2bf(b.y) << 16);
    o.w = (unsigned)f2bf(b.z) | ((unsigned)f2bf(b.w) << 16);
    xb[i] = o;   // regular store: keep warm in L2/L3 for gather
}

// ---------------- W1T'[n][k] = bf16(BETA*W1[k][n] + (k==n)*(1-BETA)) ----------------
__global__ void prep_w(const float* __restrict__ W1, unsigned short* __restrict__ W1T) {
    const float BETA = 0.40546510810816438f;
    const float OMB  = (float)(1.0 - 0.40546510810816438);
    int idx = blockIdx.x * 256 + threadIdx.x;   // 0 .. 262143
    int n = idx >> 9;
    int k = idx & 511;
    float v = BETA * W1[k * 512 + n] + (k == n ? OMB : 0.0f);
    W1T[idx] = f2bf(v);
}

// ---------------- CSR build ----------------
__global__ void zero_cnt(int* __restrict__ cnt) {
    int i = blockIdx.x * 256 + threadIdx.x;
    if (i < NN) cnt[i] = 0;
}

__global__ void hist(const int* __restrict__ ei, int* __restrict__ cnt) {
    int e = blockIdx.x * 256 + threadIdx.x;
    if (e < NE) atomicAdd(&cnt[ei[NE + e]], 1);
}

// 3-stage hierarchical exclusive scan over cnt[NN] -> rowptr/cursor
#define SCAN_B 196   // ceil(50000/256)

__global__ __launch_bounds__(256) void scan1(const int* __restrict__ cnt, int* __restrict__ bsum) {
    __shared__ int red[4];
    int t = threadIdx.x;
    int i = blockIdx.x * 256 + t;
    int v = (i < NN) ? cnt[i] : 0;
#pragma unroll
    for (int off = 32; off; off >>= 1) v += __shfl_xor(v, off, 64);
    if ((t & 63) == 0) red[t >> 6] = v;
    __syncthreads();
    if (t == 0) bsum[blockIdx.x] = red[0] + red[1] + red[2] + red[3];
}

__global__ __launch_bounds__(256) void scan2(int* __restrict__ bsum, int* __restrict__ boff) {
    __shared__ int ls[256];
    int t = threadIdx.x;
    int v = (t < SCAN_B) ? bsum[t] : 0;
    ls[t] = v;
    __syncthreads();
    for (int off = 1; off < 256; off <<= 1) {
        int add = (t >= off) ? ls[t - off] : 0;
        __syncthreads();
        ls[t] += add;
        __syncthreads();
    }
    if (t < SCAN_B) boff[t] = ls[t] - v;   // exclusive
}

__global__ __launch_bounds__(256) void scan3(const int* __restrict__ cnt, const int* __restrict__ boff,
                                             int* __restrict__ rowptr, int* __restrict__ cursor) {
    __shared__ int ls[256];
    int t = threadIdx.x;
    int i = blockIdx.x * 256 + t;
    int v = (i < NN) ? cnt[i] : 0;
    ls[t] = v;
    __syncthreads();
    for (int off = 1; off < 256; off <<= 1) {
        int add = (t >= off) ? ls[t - off] : 0;
        __syncthreads();
        ls[t] += add;
        __syncthreads();
    }
    if (i < NN) {
        int pre = ls[t] - v + boff[blockIdx.x];
        rowptr[i] = pre;
        cursor[i] = pre;
    }
}

__global__ void fill_slots(const int* __restrict__ ei, const float* __restrict__ ew,
                           int* __restrict__ cursor, int* __restrict__ esrc,
                           float* __restrict__ ewgt) {
    int e = blockIdx.x * 256 + threadIdx.x;
    if (e < NE) {
        int d = ei[NE + e];
        int p = atomicAdd(&cursor[d], 1);
        esrc[p] = ei[e];
        ewgt[p] = 0.9f * ew[e];
    }
}

// ---------------- gather: hb[node] = bf16(0.1*x0[node] + sum_e w*xb[src]) ----------------
__global__ __launch_bounds__(256) void gather_nodes(const u32x4e* __restrict__ xb,
                                                    const f32x4e* __restrict__ x0,
                                                    const int* __restrict__ rowptr,
                                                    const int* __restrict__ cnt,
                                                    const int* __restrict__ esrc,
                                                    const float* __restrict__ ewgt,
                                                    unsigned short* __restrict__ hb) {
    int node = blockIdx.x * 4 + (threadIdx.x >> 6);
    if (node >= NN) return;
    int lane = threadIdx.x & 63;

    const f32x4e* x0r = (const f32x4e*)(x0 + (size_t)node * (CH / 4));
    f32x4e a0 = __builtin_nontemporal_load(&x0r[lane * 2]);
    f32x4e a1 = __builtin_nontemporal_load(&x0r[lane * 2 + 1]);
    float acc[8];
    acc[0] = 0.1f * a0.x; acc[1] = 0.1f * a0.y; acc[2] = 0.1f * a0.z; acc[3] = 0.1f * a0.w;
    acc[4] = 0.1f * a1.x; acc[5] = 0.1f * a1.y; acc[6] = 0.1f * a1.z; acc[7] = 0.1f * a1.w;

    int beg = rowptr[node];
    int num = cnt[node];
    for (int i = beg; i < beg + num; ++i) {
        int s = esrc[i];
        float w = ewgt[i];
        u32x4e v = xb[(size_t)s * (CH / 8) + lane];
        acc[0] += w * u2f(v.x << 16);
        acc[1] += w * u2f(v.x & 0xffff0000u);
        acc[2] += w * u2f(v.y << 16);
        acc[3] += w * u2f(v.y & 0xffff0000u);
        acc[4] += w * u2f(v.z << 16);
        acc[5] += w * u2f(v.z & 0xffff0000u);
        acc[6] += w * u2f(v.w << 16);
        acc[7] += w * u2f(v.w & 0xffff0000u);
    }

    u32x4e o;
    o.x = (unsigned)f2bf(acc[0]) | ((unsigned)f2bf(acc[1]) << 16);
    o.y = (unsigned)f2bf(acc[2]) | ((unsigned)f2bf(acc[3]) << 16);
    o.z = (unsigned)f2bf(acc[4]) | ((unsigned)f2bf(acc[5]) << 16);
    o.w = (unsigned)f2bf(acc[6]) | ((unsigned)f2bf(acc[7]) << 16);
    *(u32x4e*)(hb + (size_t)node * CH + lane * 8) = o;   // regular: warm for gemm
}

// ---------------- gemm: out = hb @ W1'  (bf16 MFMA, f32 acc) ----------------
// tile 128x256, 8 waves (2x4), LDS A 16KB + B 32KB, XOR-swizzled
__global__ __launch_bounds__(512) void gemm_out(const unsigned short* __restrict__ hb,
                                                const unsigned short* __restrict__ W1T,
                                                float* __restrict__ out) {
    __shared__ unsigned short Al[128 * 64];
    __shared__ unsigned short Bl[256 * 64];
    int t = threadIdx.x;
    int lane = t & 63, w = t >> 6;
    int wm = w & 1, wn = w >> 1;           // 2 row-halves x 4 col-quads
    int rowBase = blockIdx.y * 128;
    int colBase = blockIdx.x * 256;

    f32x4 acc[4][4] = {};

    for (int k0 = 0; k0 < 512; k0 += 64) {
        // stage A: 128 rows x 64 k bf16, swizzled (2 passes, 512 thr x 16B)
#pragma unroll
        for (int p = 0; p < 2; ++p) {
            int row = p * 64 + (t >> 3);
            int k8 = (t & 7) * 8;
            // rows up to 50047 are inside hb's 50048-row allocation; tail rows
            // hold garbage but their results are never stored (guard below).
            uint4 v = *(const uint4*)(hb + (size_t)(rowBase + row) * 512 + k0 + k8);
            int addr = (row * 128 + k8 * 2) ^ ((row & 7) << 4);
            *(uint4*)((char*)Al + addr) = v;
        }
        // stage B: 256 cols x 64 k bf16, swizzled (4 passes)
#pragma unroll
        for (int p = 0; p < 4; ++p) {
            int col = p * 64 + (t >> 3);
            int k8 = (t & 7) * 8;
            uint4 v = *(const uint4*)(W1T + (size_t)(colBase + col) * 512 + k0 + k8);
            int addr = (col * 128 + k8 * 2) ^ ((col & 7) << 4);
            *(uint4*)((char*)Bl + addr) = v;
        }
        __syncthreads();

#pragma unroll
        for (int kk = 0; kk < 2; ++kk) {
            bf16x8 af[4], bfr[4];
            int kb = kk * 32 + (lane >> 4) * 8;
#pragma unroll
            for (int mi = 0; mi < 4; ++mi) {
                int row = wm * 64 + mi * 16 + (lane & 15);
                int addr = (row * 128 + kb * 2) ^ ((row & 7) << 4);
                af[mi] = *(const bf16x8*)((const char*)Al + addr);
            }
#pragma unroll
            for (int ni = 0; ni < 4; ++ni) {
                int col = wn * 64 + ni * 16 + (lane & 15);
                int addr = (col * 128 + kb * 2) ^ ((col & 7) << 4);
                bfr[ni] = *(const bf16x8*)((const char*)Bl + addr);
            }
#pragma unroll
            for (int mi = 0; mi < 4; ++mi)
#pragma unroll
                for (int ni = 0; ni < 4; ++ni)
                    acc[mi][ni] = __builtin_amdgcn_mfma_f32_16x16x32_bf16(
                        af[mi], bfr[ni], acc[mi][ni], 0, 0, 0);
        }
        __syncthreads();
    }

    // store (non-temporal): C/D mapping col=lane&15, row=(lane>>4)*4+j
#pragma unroll
    for (int mi = 0; mi < 4; ++mi) {
#pragma unroll
        for (int j = 0; j < 4; ++j) {
            int grow = rowBase + wm * 64 + mi * 16 + (lane >> 4) * 4 + j;
            if (grow < NN) {
#pragma unroll
                for (int ni = 0; ni < 4; ++ni) {
                    __builtin_nontemporal_store(
                        acc[mi][ni][j],
                        &out[(size_t)grow * 512 + colBase + wn * 64 + ni * 16 + (lane & 15)]);
                }
            }
        }
    }
}

extern "C" void kernel_launch(void* const* d_in, const int* in_sizes, int n_in,
                              void* d_out, int out_size, void* d_ws, size_t ws_size,
                              hipStream_t stream) {
    const float* x  = (const float*)d_in[0];
    const float* x0 = (const float*)d_in[1];
    const float* W1 = (const float*)d_in[2];
    const float* ew = (const float*)d_in[3];
    const int*   ei = (const int*)d_in[4];
    float* out = (float*)d_out;

    char* ws = (char*)d_ws;
    unsigned short* hb   = (unsigned short*)(ws);                        // 50048*512*2 = 51,249,152
    unsigned short* W1T  = (unsigned short*)(ws + 51249152);             // 524,288
    int*   cnt    = (int*)(ws + 51773440);                               // 200,000
    int*   rowptr = (int*)(ws + 51973440);                               // 200,000
    int*   cursor = (int*)(ws + 52173440);                               // 200,000
    int*   esrc   = (int*)(ws + 52373440);                               // 3,200,000
    float* ewgt   = (float*)(ws + 55573440);                             // 3,200,000
    int*   bsum   = (int*)(ws + 58773440);                               // 1,024
    int*   boff   = (int*)(ws + 58774464);                               // 1,024

    // xb (bf16 copy of x, 51.2 MB) lives in d_out scratch space: only read by
    // gather_nodes; gemm_out fully overwrites d_out afterwards. Recomputed
    // every call -> deterministic, no cross-call state.
    u32x4e* xb = (u32x4e*)d_out;

    // CSR build first, conv_x last: xb is the hottest data in L2/L3 when
    // gather starts.
    prep_w<<<(CH * CH) / 256, 256, 0, stream>>>(W1, W1T);
    zero_cnt<<<(NN + 255) / 256, 256, 0, stream>>>(cnt);
    hist<<<(NE + 255) / 256, 256, 0, stream>>>(ei, cnt);
    scan1<<<SCAN_B, 256, 0, stream>>>(cnt, bsum);
    scan2<<<1, 256, 0, stream>>>(bsum, boff);
    scan3<<<SCAN_B, 256, 0, stream>>>(cnt, boff, rowptr, cursor);
    fill_slots<<<(NE + 255) / 256, 256, 0, stream>>>(ei, ew, cursor, esrc, ewgt);
    conv_x<<<(NN * CH / 8 + 255) / 256, 256, 0, stream>>>((const f32x4e*)x, xb, NN * CH / 8);
    gather_nodes<<<(NN + 3) / 4, 256, 0, stream>>>(xb, (const f32x4e*)x0, rowptr, cnt, esrc, ewgt, hb);
    gemm_out<<<dim3(2, 391), 512, 0, stream>>>(hb, W1T, out);
}

// Round 7
// 303.240 us; speedup vs baseline: 1.0307x; 1.0307x over previous
//
#include <hip/hip_runtime.h>
#include <stdint.h>

#define NN 50000
#define NE 800000
#define CH 512

__device__ __forceinline__ unsigned short f2bf(float f) {
    union { float f; unsigned u; } v; v.f = f;
    unsigned u = v.u;
    unsigned r = u + 0x7FFFu + ((u >> 16) & 1u);
    return (unsigned short)(r >> 16);
}

__device__ __forceinline__ float u2f(unsigned u) {
    union { unsigned u; float f; } v; v.u = u;
    return v.f;
}

typedef short bf16x8 __attribute__((ext_vector_type(8)));
typedef float f32x4 __attribute__((ext_vector_type(4)));
typedef float f32x4e __attribute__((ext_vector_type(4)));
typedef unsigned u32x4e __attribute__((ext_vector_type(4)));

// ---------------- prologue: xb = bf16(x); W1T' transform; cnt = 0 ----------------
__global__ __launch_bounds__(256) void prologue(const f32x4e* __restrict__ x,
                                                u32x4e* __restrict__ xb,
                                                const float* __restrict__ W1,
                                                unsigned short* __restrict__ W1T,
                                                int* __restrict__ cnt) {
    int gid = blockIdx.x * 256 + threadIdx.x;   // 0 .. 3,199,999
    // conv_x: 3.2M uint4 items
    {
        f32x4e a = __builtin_nontemporal_load(&x[2 * gid]);
        f32x4e b = __builtin_nontemporal_load(&x[2 * gid + 1]);
        u32x4e o;
        o.x = (unsigned)f2bf(a.x) | ((unsigned)f2bf(a.y) << 16);
        o.y = (unsigned)f2bf(a.z) | ((unsigned)f2bf(a.w) << 16);
        o.z = (unsigned)f2bf(b.x) | ((unsigned)f2bf(b.y) << 16);
        o.w = (unsigned)f2bf(b.z) | ((unsigned)f2bf(b.w) << 16);
        xb[gid] = o;
    }
    if (gid < CH * CH) {
        const float BETA = 0.40546510810816438f;
        const float OMB  = (float)(1.0 - 0.40546510810816438);
        int n = gid >> 9;
        int k = gid & 511;
        float v = BETA * W1[k * 512 + n] + (k == n ? OMB : 0.0f);
        W1T[gid] = f2bf(v);
    }
    if (gid < NN) cnt[gid] = 0;
}

// ---------------- CSR build ----------------
__global__ void hist(const int* __restrict__ ei, int* __restrict__ cnt) {
    int e = blockIdx.x * 256 + threadIdx.x;
    if (e < NE) atomicAdd(&cnt[ei[NE + e]], 1);
}

#define SCAN_B 196   // ceil(50000/256)

__global__ __launch_bounds__(256) void scan1(const int* __restrict__ cnt, int* __restrict__ bsum) {
    __shared__ int red[4];
    int t = threadIdx.x;
    int i = blockIdx.x * 256 + t;
    int v = (i < NN) ? cnt[i] : 0;
#pragma unroll
    for (int off = 32; off; off >>= 1) v += __shfl_xor(v, off, 64);
    if ((t & 63) == 0) red[t >> 6] = v;
    __syncthreads();
    if (t == 0) bsum[blockIdx.x] = red[0] + red[1] + red[2] + red[3];
}

__global__ __launch_bounds__(256) void scan2(int* __restrict__ bsum, int* __restrict__ boff) {
    __shared__ int ls[256];
    int t = threadIdx.x;
    int v = (t < SCAN_B) ? bsum[t] : 0;
    ls[t] = v;
    __syncthreads();
    for (int off = 1; off < 256; off <<= 1) {
        int add = (t >= off) ? ls[t - off] : 0;
        __syncthreads();
        ls[t] += add;
        __syncthreads();
    }
    if (t < SCAN_B) boff[t] = ls[t] - v;   // exclusive
}

__global__ __launch_bounds__(256) void scan3(const int* __restrict__ cnt, const int* __restrict__ boff,
                                             int* __restrict__ rowptr, int* __restrict__ cursor) {
    __shared__ int ls[256];
    int t = threadIdx.x;
    int i = blockIdx.x * 256 + t;
    int v = (i < NN) ? cnt[i] : 0;
    ls[t] = v;
    __syncthreads();
    for (int off = 1; off < 256; off <<= 1) {
        int add = (t >= off) ? ls[t - off] : 0;
        __syncthreads();
        ls[t] += add;
        __syncthreads();
    }
    if (i < NN) {
        int pre = ls[t] - v + boff[blockIdx.x];
        rowptr[i] = pre;
        cursor[i] = pre;
    }
}

// (src, bits(0.9*w)) packed per slot: one 8B load per edge in gather
__global__ void fill_slots(const int* __restrict__ ei, const float* __restrict__ ew,
                           int* __restrict__ cursor, int2* __restrict__ eiw) {
    int e = blockIdx.x * 256 + threadIdx.x;
    if (e < NE) {
        int d = ei[NE + e];
        int p = atomicAdd(&cursor[d], 1);
        int2 sw;
        sw.x = ei[e];
        sw.y = __float_as_int(0.9f * ew[e]);
        eiw[p] = sw;
    }
}

// ---------------- gather: hb[node] = bf16(0.1*x0[node] + sum_e w*xb[src]) ----------------
// batched x8 for memory-level parallelism: 8 independent 1KB row loads in flight
__global__ __launch_bounds__(256) void gather_nodes(const u32x4e* __restrict__ xb,
                                                    const f32x4e* __restrict__ x0,
                                                    const int* __restrict__ rowptr,
                                                    const int* __restrict__ cnt,
                                                    const int2* __restrict__ eiw,
                                                    unsigned short* __restrict__ hb) {
    int node = blockIdx.x * 4 + (threadIdx.x >> 6);
    if (node >= NN) return;
    int lane = threadIdx.x & 63;

    const f32x4e* x0r = (const f32x4e*)(x0 + (size_t)node * (CH / 4));
    f32x4e a0 = __builtin_nontemporal_load(&x0r[lane * 2]);
    f32x4e a1 = __builtin_nontemporal_load(&x0r[lane * 2 + 1]);
    float acc[8];
    acc[0] = 0.1f * a0.x; acc[1] = 0.1f * a0.y; acc[2] = 0.1f * a0.z; acc[3] = 0.1f * a0.w;
    acc[4] = 0.1f * a1.x; acc[5] = 0.1f * a1.y; acc[6] = 0.1f * a1.z; acc[7] = 0.1f * a1.w;

    int i = rowptr[node];
    int end = i + cnt[node];

#define ACCUM(vv, ww)                                    \
    acc[0] += (ww) * u2f((vv).x << 16);                  \
    acc[1] += (ww) * u2f((vv).x & 0xffff0000u);          \
    acc[2] += (ww) * u2f((vv).y << 16);                  \
    acc[3] += (ww) * u2f((vv).y & 0xffff0000u);          \
    acc[4] += (ww) * u2f((vv).z << 16);                  \
    acc[5] += (ww) * u2f((vv).z & 0xffff0000u);          \
    acc[6] += (ww) * u2f((vv).w << 16);                  \
    acc[7] += (ww) * u2f((vv).w & 0xffff0000u);

    // batch of 8: descriptors first, then 8 independent row loads
    for (; i + 8 <= end; i += 8) {
        int2 e[8];
#pragma unroll
        for (int j = 0; j < 8; ++j) e[j] = eiw[i + j];
        u32x4e v[8];
#pragma unroll
        for (int j = 0; j < 8; ++j) v[j] = xb[(size_t)e[j].x * (CH / 8) + lane];
#pragma unroll
        for (int j = 0; j < 8; ++j) { float w = __int_as_float(e[j].y); ACCUM(v[j], w) }
    }
    // batch of 2 tail
    for (; i + 2 <= end; i += 2) {
        int2 e0 = eiw[i], e1 = eiw[i + 1];
        u32x4e v0 = xb[(size_t)e0.x * (CH / 8) + lane];
        u32x4e v1 = xb[(size_t)e1.x * (CH / 8) + lane];
        float w0 = __int_as_float(e0.y), w1 = __int_as_float(e1.y);
        ACCUM(v0, w0)
        ACCUM(v1, w1)
    }
    // single tail
    for (; i < end; ++i) {
        int2 e0 = eiw[i];
        u32x4e v0 = xb[(size_t)e0.x * (CH / 8) + lane];
        float w0 = __int_as_float(e0.y);
        ACCUM(v0, w0)
    }
#undef ACCUM

    u32x4e o;
    o.x = (unsigned)f2bf(acc[0]) | ((unsigned)f2bf(acc[1]) << 16);
    o.y = (unsigned)f2bf(acc[2]) | ((unsigned)f2bf(acc[3]) << 16);
    o.z = (unsigned)f2bf(acc[4]) | ((unsigned)f2bf(acc[5]) << 16);
    o.w = (unsigned)f2bf(acc[6]) | ((unsigned)f2bf(acc[7]) << 16);
    *(u32x4e*)(hb + (size_t)node * CH + lane * 8) = o;
}

// ---------------- gemm: out = hb @ W1'  (bf16 MFMA, f32 acc) ----------------
// tile 128x256, 8 waves (2x4), LDS A 16KB + B 32KB, XOR-swizzled
__global__ __launch_bounds__(512) void gemm_out(const unsigned short* __restrict__ hb,
                                                const unsigned short* __restrict__ W1T,
                                                float* __restrict__ out) {
    __shared__ unsigned short Al[128 * 64];
    __shared__ unsigned short Bl[256 * 64];
    int t = threadIdx.x;
    int lane = t & 63, w = t >> 6;
    int wm = w & 1, wn = w >> 1;           // 2 row-halves x 4 col-quads
    int rowBase = blockIdx.y * 128;
    int colBase = blockIdx.x * 256;

    f32x4 acc[4][4] = {};

    for (int k0 = 0; k0 < 512; k0 += 64) {
#pragma unroll
        for (int p = 0; p < 2; ++p) {
            int row = p * 64 + (t >> 3);
            int k8 = (t & 7) * 8;
            uint4 v = *(const uint4*)(hb + (size_t)(rowBase + row) * 512 + k0 + k8);
            int addr = (row * 128 + k8 * 2) ^ ((row & 7) << 4);
            *(uint4*)((char*)Al + addr) = v;
        }
#pragma unroll
        for (int p = 0; p < 4; ++p) {
            int col = p * 64 + (t >> 3);
            int k8 = (t & 7) * 8;
            uint4 v = *(const uint4*)(W1T + (size_t)(colBase + col) * 512 + k0 + k8);
            int addr = (col * 128 + k8 * 2) ^ ((col & 7) << 4);
            *(uint4*)((char*)Bl + addr) = v;
        }
        __syncthreads();

#pragma unroll
        for (int kk = 0; kk < 2; ++kk) {
            bf16x8 af[4], bfr[4];
            int kb = kk * 32 + (lane >> 4) * 8;
#pragma unroll
            for (int mi = 0; mi < 4; ++mi) {
                int row = wm * 64 + mi * 16 + (lane & 15);
                int addr = (row * 128 + kb * 2) ^ ((row & 7) << 4);
                af[mi] = *(const bf16x8*)((const char*)Al + addr);
            }
#pragma unroll
            for (int ni = 0; ni < 4; ++ni) {
                int col = wn * 64 + ni * 16 + (lane & 15);
                int addr = (col * 128 + kb * 2) ^ ((col & 7) << 4);
                bfr[ni] = *(const bf16x8*)((const char*)Bl + addr);
            }
#pragma unroll
            for (int mi = 0; mi < 4; ++mi)
#pragma unroll
                for (int ni = 0; ni < 4; ++ni)
                    acc[mi][ni] = __builtin_amdgcn_mfma_f32_16x16x32_bf16(
                        af[mi], bfr[ni], acc[mi][ni], 0, 0, 0);
        }
        __syncthreads();
    }

#pragma unroll
    for (int mi = 0; mi < 4; ++mi) {
#pragma unroll
        for (int j = 0; j < 4; ++j) {
            int grow = rowBase + wm * 64 + mi * 16 + (lane >> 4) * 4 + j;
            if (grow < NN) {
#pragma unroll
                for (int ni = 0; ni < 4; ++ni) {
                    __builtin_nontemporal_store(
                        acc[mi][ni][j],
                        &out[(size_t)grow * 512 + colBase + wn * 64 + ni * 16 + (lane & 15)]);
                }
            }
        }
    }
}

extern "C" void kernel_launch(void* const* d_in, const int* in_sizes, int n_in,
                              void* d_out, int out_size, void* d_ws, size_t ws_size,
                              hipStream_t stream) {
    const float* x  = (const float*)d_in[0];
    const float* x0 = (const float*)d_in[1];
    const float* W1 = (const float*)d_in[2];
    const float* ew = (const float*)d_in[3];
    const int*   ei = (const int*)d_in[4];
    float* out = (float*)d_out;

    char* ws = (char*)d_ws;
    unsigned short* hb   = (unsigned short*)(ws);                        // 50048*512*2 = 51,249,152
    unsigned short* W1T  = (unsigned short*)(ws + 51249152);             // 524,288
    int*   cnt    = (int*)(ws + 51773440);                               // 200,000
    int*   rowptr = (int*)(ws + 51973440);                               // 200,000
    int*   cursor = (int*)(ws + 52173440);                               // 200,000
    int2*  eiw    = (int2*)(ws + 52373440);                              // 6,400,000
    int*   bsum   = (int*)(ws + 58773440);                               // 1,024
    int*   boff   = (int*)(ws + 58774464);                               // 1,024

    // xb (bf16 copy of x, 51.2 MB) lives in d_out scratch space: only read by
    // gather_nodes; gemm_out fully overwrites d_out afterwards.
    u32x4e* xb = (u32x4e*)d_out;

    prologue<<<NN * CH / 8 / 256, 256, 0, stream>>>((const f32x4e*)x, xb, W1, W1T, cnt);
    hist<<<(NE + 255) / 256, 256, 0, stream>>>(ei, cnt);
    scan1<<<SCAN_B, 256, 0, stream>>>(cnt, bsum);
    scan2<<<1, 256, 0, stream>>>(bsum, boff);
    scan3<<<SCAN_B, 256, 0, stream>>>(cnt, boff, rowptr, cursor);
    fill_slots<<<(NE + 255) / 256, 256, 0, stream>>>(ei, ew, cursor, eiw);
    gather_nodes<<<(NN + 3) / 4, 256, 0, stream>>>(xb, (const f32x4e*)x0, rowptr, cnt, eiw, hb);
    gemm_out<<<dim3(2, 391), 512, 0, stream>>>(hb, W1T, out);
}